// Round 8
// baseline (193.672 us; speedup 1.0000x reference)
//
#include <hip/hip_runtime.h>
#include <math.h>

// ProjectionLayer: out[b,t,gx,gy] = data[b,t, argmin_n ||locs[b,n]*25+25 - (gx,gy)|| ]
// B=64, T=1024, N=256 sensors, G=50 (2500 grid cells).
// Stage 1 (nearest_k): 41M distance evals -> nearest[b,g] in d_ws (640 KB).
// Stage 2 (gather_lds_k): 512 blocks x 256 thr (2/CU), each block owns a
//   CONTIGUOUS 1.28 MB output slab (XCD-contiguous mapping); double-buffered
//   LDS staging, ONE raw barrier per chunk (lgkmcnt only -- prefetch loads
//   stay in flight), b32 LDS gather, coalesced float4 stores.
// R1: scattered GLOBAL loads ~1 lane/cyc in TA -> LDS.      (407->200 us)
// R2/R4: TLP 4->8 blocks/CU NEUTRAL.                        (200->207)
// R5: drain-free barriers NEUTRAL (at 8 blocks/CU).         (207)
// R6: 4x fewer LDS ops (b128) NEUTRAL -> LDS exonerated.    (209)
// R7 WIN: 256 long contiguous write streams (1/CU).         (209->179)
// R8 theory: at 1 block/CU the 2x-per-chunk __syncthreads (vmcnt(0) drain!)
//   exposes stage+prefetch latency with nothing to cover it (~25 us).
//   dbuf + single lgkm-only barrier + 2 blocks/CU to cover barrier stalls.

#define GRIDG  50
#define GG     2500   // GRIDG*GRIDG
#define GQ     625    // GG/4 (float4 groups per output row)
#define NS     256    // sensors
#define TT     1024
#define BB     64
#define TCHUNK 128    // t rows per block (1.28 MB contiguous slab)
#define RSTG   16     // rows staged in LDS per buffer (16 KB)
#define NCH    (TCHUNK / RSTG)   // 8

// post-ds_write barrier: LDS visibility only; global loads/stores NOT drained
#define BAR_LDS()  asm volatile("s_waitcnt lgkmcnt(0)\n\ts_barrier" ::: "memory")

// exact replication of reference fp32 arithmetic: unfused mul/add + rounded sqrt
__device__ __forceinline__ float ref_dist(float lx, float ly, float gx, float gy) {
    const float dx = lx - gx;
    const float dy = ly - gy;
    const float s  = __fadd_rn(__fmul_rn(dx, dx), __fmul_rn(dy, dy));
    return __fsqrt_rn(s);
}

// ---- Stage 1: nearest sensor index per grid cell -----------------------------
__global__ __launch_bounds__(256) void nearest_k(const float* __restrict__ locs,
                                                 int* __restrict__ nearest) {
    __shared__ float lsx[NS];
    __shared__ float lsy[NS];
    const int b   = blockIdx.x / 10;   // 10 blocks of 256 cover 2500 cells
    const int gc  = blockIdx.x % 10;
    const int tid = threadIdx.x;

    const float2 l = ((const float2*)locs)[b * NS + tid];
    lsx[tid] = __fadd_rn(__fmul_rn(l.x, 25.0f), 25.0f);
    lsy[tid] = __fadd_rn(__fmul_rn(l.y, 25.0f), 25.0f);
    __syncthreads();

    const int g = gc * 256 + tid;
    if (g >= GG) return;
    const float gx = (float)(g / GRIDG);
    const float gy = (float)(g % GRIDG);

    float best = 1.0e30f;
    int   bi   = 0;
    #pragma unroll 4
    for (int n = 0; n < NS; ++n) {          // ascending n + strict '<'  => first-index
        const float d = ref_dist(lsx[n], lsy[n], gx, gy);   //    tie-break == jnp.argmin
        if (d < best) { best = d; bi = n; }
    }
    nearest[b * GG + g] = bi;
}

// ---- Stage 2: contiguous slab per block, dbuf LDS, 1 barrier/chunk ----------
__global__ __launch_bounds__(256) void gather_lds_k(const float* __restrict__ data,
                                                    const int* __restrict__ nearest,
                                                    float* __restrict__ out) {
    __shared__ float rows[2][RSTG * NS];   // 2 x 16 KB
    const int tid = threadIdx.x;
    const int l   = blockIdx.x;
    // XCD-contiguous slab mapping: XCD k (blocks l%8==k) covers batches
    // [8k, 8k+8) -> one contiguous 80 MB output region per XCD.
    const int sb  = (l & 7) * 64 + (l >> 3);   // 512 slabs
    const int b   = sb >> 3;                   // batch
    const int t0  = (sb & 7) * TCHUNK;         // eighth of T

    // per-thread gather indices (loop-invariant over t) -> registers
    const int4 iv0 = ((const int4*)nearest)[b * GQ + tid];
    const int4 iv1 = ((const int4*)nearest)[b * GQ + 256 + tid];
    const int4 iv2 = (tid < GQ - 512)
                   ? ((const int4*)nearest)[b * GQ + 512 + tid]
                   : make_int4(0, 0, 0, 0);

    const float4* __restrict__ dbase = (const float4*)data + (size_t)b * TT * (NS / 4);
    float4*       __restrict__ obase = (float4*)out + (size_t)b * TT * GQ;

    // prologue prefetch: chunk 0 (16 rows = 1024 float4 = 4/thread, coalesced)
    const float4* __restrict__ src = dbase + (size_t)t0 * (NS / 4);
    float4 pr[4];
    #pragma unroll
    for (int i = 0; i < 4; ++i) pr[i] = src[tid + i * 256];

    for (int c = 0; c < NCH; ++c) {
        // commit prefetched chunk to LDS buffer c&1 (vmcnt waits land here,
        // hidden under previous chunk's gather stores)
        float4* __restrict__ buf = (float4*)rows[c & 1];
        #pragma unroll
        for (int i = 0; i < 4; ++i) buf[tid + i * 256] = pr[i];
        // issue next chunk's loads early (in flight across barrier + gather)
        if (c + 1 < NCH) {
            src += RSTG * (NS / 4);
            #pragma unroll
            for (int i = 0; i < 4; ++i) pr[i] = src[tid + i * 256];
        }
        BAR_LDS();   // single barrier per chunk; stores/loads stay in flight
        // safety: buf[c&1] was last read in chunk c-2; those ds_reads fed
        // stores issued before barrier(c-1), so reads completed before it.

        const int ts = t0 + c * RSTG;
        const float* __restrict__ base = rows[c & 1];
        #pragma unroll
        for (int r = 0; r < RSTG; ++r) {
            const float* __restrict__ row  = base + r * NS;
            float4*      __restrict__ orow = obase + (size_t)(ts + r) * GQ;
            float4 v;
            v.x = row[iv0.x]; v.y = row[iv0.y]; v.z = row[iv0.z]; v.w = row[iv0.w];
            orow[tid] = v;                          // coalesced 16B/lane store
            float4 u;
            u.x = row[iv1.x]; u.y = row[iv1.y]; u.z = row[iv1.z]; u.w = row[iv1.w];
            orow[256 + tid] = u;
            if (tid < GQ - 512) {
                float4 w;
                w.x = row[iv2.x]; w.y = row[iv2.y]; w.z = row[iv2.z]; w.w = row[iv2.w];
                orow[512 + tid] = w;
            }
        }
    }
}

// ---- Fallback: fused (only if ws too small for the 640 KB index buffer) -----
__global__ __launch_bounds__(256) void fused_k(const float* __restrict__ data,
                                               const float* __restrict__ locs,
                                               float* __restrict__ out) {
    __shared__ float lsx[NS];
    __shared__ float lsy[NS];
    const int b   = blockIdx.z;
    const int tid = threadIdx.x;
    const float2 l = ((const float2*)locs)[b * NS + tid];
    lsx[tid] = __fadd_rn(__fmul_rn(l.x, 25.0f), 25.0f);
    lsy[tid] = __fadd_rn(__fmul_rn(l.y, 25.0f), 25.0f);
    __syncthreads();

    const int gq = blockIdx.x * 256 + tid;
    if (gq >= GQ) return;

    int iv[4];
    #pragma unroll
    for (int k = 0; k < 4; ++k) {
        const int g  = gq * 4 + k;
        const float gx = (float)(g / GRIDG);
        const float gy = (float)(g % GRIDG);
        float best = 1.0e30f;
        int   bi   = 0;
        for (int n = 0; n < NS; ++n) {
            const float d = ref_dist(lsx[n], lsy[n], gx, gy);
            if (d < best) { best = d; bi = n; }
        }
        iv[k] = bi;
    }

    const int t0 = blockIdx.y * (TT / 2);
    const float* __restrict__ dbase = data + (size_t)b * TT * NS;
    float4*      __restrict__ obase = (float4*)out + (size_t)b * TT * GQ + gq;
    #pragma unroll 4
    for (int t = t0; t < t0 + TT / 2; ++t) {
        const float* __restrict__ row = dbase + t * NS;
        float4 v;
        v.x = row[iv[0]];
        v.y = row[iv[1]];
        v.z = row[iv[2]];
        v.w = row[iv[3]];
        obase[(size_t)t * GQ] = v;
    }
}

extern "C" void kernel_launch(void* const* d_in, const int* in_sizes, int n_in,
                              void* d_out, int out_size, void* d_ws, size_t ws_size,
                              hipStream_t stream) {
    const float* data = (const float*)d_in[0];   // [64,1024,256] f32
    const float* locs = (const float*)d_in[1];   // [64,256,2]    f32
    float*       out  = (float*)d_out;           // [64,1024,50,50] f32
    (void)in_sizes; (void)n_in; (void)out_size;

    const size_t idx_bytes = (size_t)BB * GG * sizeof(int);   // 640 KB
    if (ws_size >= idx_bytes) {
        int* nearest = (int*)d_ws;
        nearest_k<<<dim3(BB * 10), 256, 0, stream>>>(locs, nearest);
        gather_lds_k<<<dim3(BB * 8), 256, 0, stream>>>(data, nearest, out);
    } else {
        fused_k<<<dim3(3, 2, BB), 256, 0, stream>>>(data, locs, out);
    }
}

// Round 9
// 175.187 us; speedup vs baseline: 1.1055x; 1.1055x over previous
//
#include <hip/hip_runtime.h>
#include <math.h>

// ProjectionLayer: out[b,t,gx,gy] = data[b,t, argmin_n ||locs[b,n]*25+25 - (gx,gy)|| ]
// B=64, T=1024, N=256 sensors, G=50 (2500 grid cells).
// Stage 1 (nearest_k): 41M distance evals -> nearest[b,g] in d_ws (640 KB).
// Stage 2 (gather_lds_k): 128 blocks x 512 thr, each block owns a CONTIGUOUS
//   5.12 MB output slab (XCD-contiguous mapping); LDS-staged b32 gather,
//   coalesced float4 stores. 655 MB W + 67 MB R.
// R1: scattered GLOBAL loads ~1 lane/cyc in TA -> LDS.      (407->200 us)
// R2/R4: TLP 4->8 blocks/CU NEUTRAL.                        (200->207)
// R5: drain-free barriers NEUTRAL (at 8 blocks/CU).         (207)
// R6: 4x fewer LDS ops (b128) NEUTRAL -> LDS exonerated.    (209)
// R7 WIN: 256 long contiguous write streams (1/CU).         (209->179)
// R8: 512 streams REGRESSED (194) -> concurrent-write-stream count is the
//   dominant variable, monotone: 2048:209 / 1024:200 / 512:194 / 256:179.
// R9: halve again -> 128 streams x 5.12 MB. Discriminator: DRAM-stream-
//   limited -> ~160-170; CU-issue-limited (128 CUs @ ~20 B/cyc) -> regress.

#define GRIDG  50
#define GG     2500   // GRIDG*GRIDG
#define GQ     625    // GG/4 (float4 groups per output row)
#define NS     256    // sensors
#define TT     1024
#define BB     64
#define TCHUNK 512    // t rows per block (5.12 MB contiguous slab)
#define RSTG   32     // rows staged in LDS per barrier (32 KB)
#define NCH    (TCHUNK / RSTG)   // 16

// exact replication of reference fp32 arithmetic: unfused mul/add + rounded sqrt
__device__ __forceinline__ float ref_dist(float lx, float ly, float gx, float gy) {
    const float dx = lx - gx;
    const float dy = ly - gy;
    const float s  = __fadd_rn(__fmul_rn(dx, dx), __fmul_rn(dy, dy));
    return __fsqrt_rn(s);
}

// ---- Stage 1: nearest sensor index per grid cell -----------------------------
__global__ __launch_bounds__(256) void nearest_k(const float* __restrict__ locs,
                                                 int* __restrict__ nearest) {
    __shared__ float lsx[NS];
    __shared__ float lsy[NS];
    const int b   = blockIdx.x / 10;   // 10 blocks of 256 cover 2500 cells
    const int gc  = blockIdx.x % 10;
    const int tid = threadIdx.x;

    const float2 l = ((const float2*)locs)[b * NS + tid];
    lsx[tid] = __fadd_rn(__fmul_rn(l.x, 25.0f), 25.0f);
    lsy[tid] = __fadd_rn(__fmul_rn(l.y, 25.0f), 25.0f);
    __syncthreads();

    const int g = gc * 256 + tid;
    if (g >= GG) return;
    const float gx = (float)(g / GRIDG);
    const float gy = (float)(g % GRIDG);

    float best = 1.0e30f;
    int   bi   = 0;
    #pragma unroll 4
    for (int n = 0; n < NS; ++n) {          // ascending n + strict '<'  => first-index
        const float d = ref_dist(lsx[n], lsy[n], gx, gy);   //    tie-break == jnp.argmin
        if (d < best) { best = d; bi = n; }
    }
    nearest[b * GG + g] = bi;
}

// ---- Stage 2: one 5.12 MB contiguous output slab per block ------------------
__global__ __launch_bounds__(512) void gather_lds_k(const float* __restrict__ data,
                                                    const int* __restrict__ nearest,
                                                    float* __restrict__ out) {
    __shared__ float rows[RSTG * NS];   // 32 KB
    const int tid = threadIdx.x;
    const int l   = blockIdx.x;
    // XCD-contiguous slab mapping: XCD k (blocks l%8==k) covers batches
    // [8k, 8k+8) -> one contiguous 80 MB output region per XCD.
    const int sb  = (l & 7) * 16 + (l >> 3);   // 128 slabs
    const int b   = sb >> 1;                   // batch
    const int t0  = (sb & 1) * TCHUNK;         // half of T

    // per-thread gather indices (loop-invariant over t) -> registers
    const int4 iv0 = ((const int4*)nearest)[b * GQ + tid];          // tid<512<=GQ
    const int4 iv1 = (tid < GQ - 512)
                   ? ((const int4*)nearest)[b * GQ + 512 + tid]
                   : make_int4(0, 0, 0, 0);

    const float4* __restrict__ dbase = (const float4*)data + (size_t)b * TT * (NS / 4);
    float4*       __restrict__ obase = (float4*)out + (size_t)b * TT * GQ;

    // prologue prefetch: chunk 0 (32 rows = 2048 float4 = 4/thread, coalesced)
    const float4* __restrict__ src = dbase + (size_t)t0 * (NS / 4);
    float4 pr[4];
    #pragma unroll
    for (int i = 0; i < 4; ++i) pr[i] = src[tid + i * 512];

    for (int c = 0; c < NCH; ++c) {
        __syncthreads();   // previous chunk fully consumed
        #pragma unroll
        for (int i = 0; i < 4; ++i) ((float4*)rows)[tid + i * 512] = pr[i];
        // issue next chunk's loads early (in flight across the gather below)
        if (c + 1 < NCH) {
            src += RSTG * (NS / 4);
            #pragma unroll
            for (int i = 0; i < 4; ++i) pr[i] = src[tid + i * 512];
        }
        __syncthreads();   // staged rows visible

        const int ts = t0 + c * RSTG;
        #pragma unroll 4
        for (int r = 0; r < RSTG; ++r) {
            const float* __restrict__ row  = rows + r * NS;
            float4*      __restrict__ orow = obase + (size_t)(ts + r) * GQ;
            float4 v;
            v.x = row[iv0.x]; v.y = row[iv0.y]; v.z = row[iv0.z]; v.w = row[iv0.w];
            orow[tid] = v;                          // coalesced 16B/lane store
            if (tid < GQ - 512) {
                float4 u;
                u.x = row[iv1.x]; u.y = row[iv1.y]; u.z = row[iv1.z]; u.w = row[iv1.w];
                orow[512 + tid] = u;
            }
        }
    }
}

// ---- Fallback: fused (only if ws too small for the 640 KB index buffer) -----
__global__ __launch_bounds__(256) void fused_k(const float* __restrict__ data,
                                               const float* __restrict__ locs,
                                               float* __restrict__ out) {
    __shared__ float lsx[NS];
    __shared__ float lsy[NS];
    const int b   = blockIdx.z;
    const int tid = threadIdx.x;
    const float2 l = ((const float2*)locs)[b * NS + tid];
    lsx[tid] = __fadd_rn(__fmul_rn(l.x, 25.0f), 25.0f);
    lsy[tid] = __fadd_rn(__fmul_rn(l.y, 25.0f), 25.0f);
    __syncthreads();

    const int gq = blockIdx.x * 256 + tid;
    if (gq >= GQ) return;

    int iv[4];
    #pragma unroll
    for (int k = 0; k < 4; ++k) {
        const int g  = gq * 4 + k;
        const float gx = (float)(g / GRIDG);
        const float gy = (float)(g % GRIDG);
        float best = 1.0e30f;
        int   bi   = 0;
        for (int n = 0; n < NS; ++n) {
            const float d = ref_dist(lsx[n], lsy[n], gx, gy);
            if (d < best) { best = d; bi = n; }
        }
        iv[k] = bi;
    }

    const int t0 = blockIdx.y * (TT / 2);
    const float* __restrict__ dbase = data + (size_t)b * TT * NS;
    float4*      __restrict__ obase = (float4*)out + (size_t)b * TT * GQ + gq;
    #pragma unroll 4
    for (int t = t0; t < t0 + TT / 2; ++t) {
        const float* __restrict__ row = dbase + t * NS;
        float4 v;
        v.x = row[iv[0]];
        v.y = row[iv[1]];
        v.z = row[iv[2]];
        v.w = row[iv[3]];
        obase[(size_t)t * GQ] = v;
    }
}

extern "C" void kernel_launch(void* const* d_in, const int* in_sizes, int n_in,
                              void* d_out, int out_size, void* d_ws, size_t ws_size,
                              hipStream_t stream) {
    const float* data = (const float*)d_in[0];   // [64,1024,256] f32
    const float* locs = (const float*)d_in[1];   // [64,256,2]    f32
    float*       out  = (float*)d_out;           // [64,1024,50,50] f32
    (void)in_sizes; (void)n_in; (void)out_size;

    const size_t idx_bytes = (size_t)BB * GG * sizeof(int);   // 640 KB
    if (ws_size >= idx_bytes) {
        int* nearest = (int*)d_ws;
        nearest_k<<<dim3(BB * 10), 256, 0, stream>>>(locs, nearest);
        gather_lds_k<<<dim3(BB * 2), 512, 0, stream>>>(data, nearest, out);
    } else {
        fused_k<<<dim3(3, 2, BB), 256, 0, stream>>>(data, locs, out);
    }
}